// Round 7
// baseline (418.923 us; speedup 1.0000x reference)
//
#include <hip/hip_runtime.h>
#include <math.h>

#define D_MODEL 300
#define LSEQ    512
#define NBATCH  300
#define VOCAB   32000
#define NENT    (NBATCH * LSEQ)     // 153600 (i,l) entries
#define KCH     75                  // e-chunk width (300 = 4*75)
#define ECH     4                   // e-chunks
#define NBLK    64                  // entry-chunk splits for scatter
#define EPB     (NENT / NBLK)       // 2400 entries per scatter block
#define TI      6                   // i-rows per termB block
#define JPB     2                   // j-rows per fc1 block
#define SCALE   17.32050807568877f  // sqrt(300)
#define C2      0.030701134573253947f  // ln(10000)/300
#define PIH     1.5707963267948966f

// ---- pass 1: histogram of x1 values ----
__global__ void count_kernel(const int* __restrict__ x1, int* __restrict__ cnt) {
    int idx = blockIdx.x * 256 + threadIdx.x;
    if (idx < NENT) atomicAdd(&cnt[x1[idx]], 1);
}

// ---- pass 2: exclusive scan over 32000 bins (single block, 1024 thr, 32 bins/thr) ----
__global__ __launch_bounds__(1024) void scan_kernel(const int* __restrict__ cnt,
                                                    int* __restrict__ cur) {
    __shared__ int lds[1024];
    const int t = threadIdx.x;
    const int v0 = t * 32;
    int local[32];
    int tot = 0;
    #pragma unroll
    for (int k = 0; k < 32; ++k) {
        int v = v0 + k;
        int c = (v < VOCAB) ? cnt[v] : 0;
        local[k] = tot;           // exclusive within thread
        tot += c;
    }
    lds[t] = tot;
    __syncthreads();
    int mysum = tot;
    for (int d = 1; d < 1024; d <<= 1) {
        int add = (t >= d) ? lds[t - d] : 0;
        __syncthreads();
        lds[t] += add;
        __syncthreads();
    }
    int base = lds[t] - mysum;    // exclusive across threads
    #pragma unroll
    for (int k = 0; k < 32; ++k) {
        int v = v0 + k;
        if (v < VOCAB) cur[v] = base + local[k];
    }
}

// ---- pass 3: scatter entries into v-sorted order; entry = (v<<9|i, SCALE*S) ----
__global__ void fill_kernel(const int* __restrict__ x1, const int* __restrict__ x2,
                            const float* __restrict__ emb2, int* __restrict__ cur,
                            int2* __restrict__ entries) {
    int idx = blockIdx.x * 256 + threadIdx.x;
    if (idx >= NENT) return;
    int i = idx >> 9, l = idx & (LSEQ - 1);
    int v = x1[idx];
    float dvi = __expf(-C2 * (float)(i & ~1));
    float arg = (float)l * dvi + ((i & 1) ? PIH : 0.0f);
    float S = fmaf(emb2[(size_t)x2[idx] * D_MODEL + i], SCALE, __sinf(arg));
    int pos = atomicAdd(&cur[v], 1);
    entries[pos] = make_int2((v << 9) | i, __float_as_int(SCALE * S));
}

// ---- term A scatter: v-sorted entries -> emb1 rows are (nearly) streamed.
// Block = (entry-chunk bx, e-chunk ec). LDS-private acc[300][75] (90 KB), ds_add_f32.
// Flush to partial buffer P (no global atomics).
__global__ __launch_bounds__(512) void scatter_kernel(const float* __restrict__ emb1,
                                                      const int2* __restrict__ entries,
                                                      float* __restrict__ P) {
    __shared__ float acc[NBATCH * KCH];   // 22500 floats = 90 KB
    const int tid = threadIdx.x;
    const int bx  = blockIdx.x;           // entry chunk
    const int ec  = blockIdx.y;           // e chunk
    const int e0  = ec * KCH;

    for (int p = tid; p < NBATCH * KCH; p += 512) acc[p] = 0.0f;
    __syncthreads();

    if (tid < 450) {                      // 6 groups x 75 lanes
        const int g    = tid / 75;
        const int lane = tid - g * 75;
        const float* e1l = emb1 + e0 + lane;
        const int base = bx * EPB + g;    // interleaved: groups share v-locality
        for (int m = 0; m < EPB / 6; m += 4) {
            const int2 q0 = entries[base + 6 * (m + 0)];
            const int2 q1 = entries[base + 6 * (m + 1)];
            const int2 q2 = entries[base + 6 * (m + 2)];
            const int2 q3 = entries[base + 6 * (m + 3)];
            const float r0 = e1l[(size_t)(q0.x >> 9) * D_MODEL];
            const float r1 = e1l[(size_t)(q1.x >> 9) * D_MODEL];
            const float r2 = e1l[(size_t)(q2.x >> 9) * D_MODEL];
            const float r3 = e1l[(size_t)(q3.x >> 9) * D_MODEL];
            atomicAdd(&acc[(q0.x & 511) * KCH + lane], __int_as_float(q0.y) * r0);
            atomicAdd(&acc[(q1.x & 511) * KCH + lane], __int_as_float(q1.y) * r1);
            atomicAdd(&acc[(q2.x & 511) * KCH + lane], __int_as_float(q2.y) * r2);
            atomicAdd(&acc[(q3.x & 511) * KCH + lane], __int_as_float(q3.y) * r3);
        }
    }
    __syncthreads();

    float* myP = P + (size_t)(ec * NBLK + bx) * (NBATCH * KCH);
    for (int p = tid; p < NBATCH * KCH; p += 512) myP[p] = acc[p];
}

// ---- reduce partials: Dm[i][e] = sum_b P[b][i][e-slice]  (plain stores, termA only) ----
__global__ void reduce_kernel(const float* __restrict__ P, float* __restrict__ Dm) {
    const int p  = blockIdx.x * 256 + threadIdx.x;
    const int ec = blockIdx.y;
    if (p >= NBATCH * KCH) return;
    float s = 0.0f;
    #pragma unroll 8
    for (int b = 0; b < NBLK; ++b)
        s += P[(size_t)(ec * NBLK + b) * (NBATCH * KCH) + p];
    const int i = p / KCH, c = p - i * KCH;
    Dm[i * D_MODEL + ec * KCH + c] = s;
}

// ---- term B: Dm[i][e] += sum_l S[i,l] * pe[l][e]; pe in-register, sin shared across TI i's ----
__global__ void termB_kernel(const int* __restrict__ x2, const float* __restrict__ emb2,
                             float* __restrict__ Dm) {
    __shared__ float sS[TI][64];
    const int i0  = blockIdx.x * TI;
    const int l0  = blockIdx.y * 64;
    const int tid = threadIdx.x;

    for (int t = tid; t < TI * 64; t += 320) {
        const int ti = t >> 6, lr = t & 63;
        const int gi = i0 + ti, gl = l0 + lr;
        const float dvi = __expf(-C2 * (float)(gi & ~1));
        const float arg = (float)gl * dvi + ((gi & 1) ? PIH : 0.0f);
        sS[ti][lr] = fmaf(emb2[(size_t)x2[gi * LSEQ + gl] * D_MODEL + gi], SCALE, __sinf(arg));
    }
    __syncthreads();

    if (tid < D_MODEL) {
        const float dv = __expf(-C2 * (float)(tid & ~1));
        const float ph = (tid & 1) ? PIH : 0.0f;
        float a0 = 0.f, a1 = 0.f, a2 = 0.f, a3 = 0.f, a4 = 0.f, a5 = 0.f;
        #pragma unroll 8
        for (int l = 0; l < 64; ++l) {
            const float pv = __sinf((float)(l0 + l) * dv + ph);
            a0 = fmaf(sS[0][l], pv, a0);
            a1 = fmaf(sS[1][l], pv, a1);
            a2 = fmaf(sS[2][l], pv, a2);
            a3 = fmaf(sS[3][l], pv, a3);
            a4 = fmaf(sS[4][l], pv, a4);
            a5 = fmaf(sS[5][l], pv, a5);
        }
        atomicAdd(&Dm[(i0 + 0) * D_MODEL + tid], a0);
        atomicAdd(&Dm[(i0 + 1) * D_MODEL + tid], a1);
        atomicAdd(&Dm[(i0 + 2) * D_MODEL + tid], a2);
        atomicAdd(&Dm[(i0 + 3) * D_MODEL + tid], a3);
        atomicAdd(&Dm[(i0 + 4) * D_MODEL + tid], a4);
        atomicAdd(&Dm[(i0 + 5) * D_MODEL + tid], a5);
    }
}

// fc1 k-split partial: Hpre[j][e] += sum_{k in chunk} w1[j,k]*Dm[k][e]
__global__ void fc1_kernel(const float* __restrict__ w1, const float* __restrict__ Dm,
                           float* __restrict__ Hpre) {
    const int j0  = blockIdx.x * JPB;
    const int sp  = blockIdx.y;
    const int tid = threadIdx.x;
    const int k0  = sp * KCH;
    if (tid >= D_MODEL) return;
    const float* w1r0 = w1 + (j0 + 0) * D_MODEL + k0;
    const float* w1r1 = w1 + (j0 + 1) * D_MODEL + k0;
    float acc0 = 0.0f, acc1 = 0.0f;
    #pragma unroll 5
    for (int k = 0; k < KCH; ++k) {
        float d = Dm[(k0 + k) * D_MODEL + tid];
        acc0 = fmaf(w1r0[k], d, acc0);
        acc1 = fmaf(w1r1[k], d, acc1);
    }
    atomicAdd(&Hpre[(j0 + 0) * D_MODEL + tid], acc0);
    atomicAdd(&Hpre[(j0 + 1) * D_MODEL + tid], acc1);
}

// Fused bias + relu + fc2 + softmax. Block = 256 = 64 e-lanes x 4 j-chunks.
__global__ void fc2_softmax_kernel(const float* __restrict__ Hpre, const float* __restrict__ b1,
                                   const float* __restrict__ w2, const float* __restrict__ b2,
                                   float* __restrict__ out) {
    __shared__ float sm[4][4][64];
    const int tid   = threadIdx.x;
    const int e_loc = tid & 63;
    const int jc    = tid >> 6;
    const int e     = blockIdx.x * 64 + e_loc;

    float a0 = 0.f, a1 = 0.f, a2 = 0.f, a3 = 0.f;
    if (e < D_MODEL) {
        const int j0 = jc * 75;
        #pragma unroll 5
        for (int j = j0; j < j0 + 75; ++j) {
            float h = fmaxf(Hpre[j * D_MODEL + e] + b1[j], 0.0f);
            a0 = fmaf(h, w2[0 * D_MODEL + j], a0);
            a1 = fmaf(h, w2[1 * D_MODEL + j], a1);
            a2 = fmaf(h, w2[2 * D_MODEL + j], a2);
            a3 = fmaf(h, w2[3 * D_MODEL + j], a3);
        }
    }
    sm[jc][0][e_loc] = a0; sm[jc][1][e_loc] = a1;
    sm[jc][2][e_loc] = a2; sm[jc][3][e_loc] = a3;
    __syncthreads();

    if (jc == 0 && e < D_MODEL) {
        float l0 = b2[0] + sm[0][0][e_loc] + sm[1][0][e_loc] + sm[2][0][e_loc] + sm[3][0][e_loc];
        float l1 = b2[1] + sm[0][1][e_loc] + sm[1][1][e_loc] + sm[2][1][e_loc] + sm[3][1][e_loc];
        float l2 = b2[2] + sm[0][2][e_loc] + sm[1][2][e_loc] + sm[2][2][e_loc] + sm[3][2][e_loc];
        float l3 = b2[3] + sm[0][3][e_loc] + sm[1][3][e_loc] + sm[2][3][e_loc] + sm[3][3][e_loc];
        float m  = fmaxf(fmaxf(l0, l1), fmaxf(l2, l3));
        float x0 = expf(l0 - m), x1 = expf(l1 - m), x2 = expf(l2 - m), x3 = expf(l3 - m);
        float inv = 1.0f / (x0 + x1 + x2 + x3);
        out[e * 4 + 0] = x0 * inv;
        out[e * 4 + 1] = x1 * inv;
        out[e * 4 + 2] = x2 * inv;
        out[e * 4 + 3] = x3 * inv;
    }
}

extern "C" void kernel_launch(void* const* d_in, const int* in_sizes, int n_in,
                              void* d_out, int out_size, void* d_ws, size_t ws_size,
                              hipStream_t stream) {
    const int*   x1   = (const int*)d_in[0];
    const int*   x2   = (const int*)d_in[1];
    const float* emb1 = (const float*)d_in[2];
    const float* emb2 = (const float*)d_in[3];
    const float* w1   = (const float*)d_in[4];
    const float* b1   = (const float*)d_in[5];
    const float* w2   = (const float*)d_in[6];
    const float* b2   = (const float*)d_in[7];
    float* out = (float*)d_out;

    char* ws = (char*)d_ws;
    int*   cnt     = (int*)ws;                        // 32000*4  = 128000
    float* Hpre    = (float*)(ws + 128000);           // 90000*4  = 360000
    int*   cur     = (int*)(ws + 488000);             // 32000*4  = 128000
    int2*  entries = (int2*)(ws + 616000);            // 153600*8 = 1228800
    float* P       = (float*)(ws + 1844800);          // 256*22500*4 = 23040000
    float* Dm      = (float*)(ws + 24884800);         // 90000*4  = 360000

    // zero cnt + Hpre (contiguous)
    (void)hipMemsetAsync(ws, 0, 488000, stream);

    count_kernel<<<(NENT + 255) / 256, 256, 0, stream>>>(x1, cnt);
    scan_kernel<<<1, 1024, 0, stream>>>(cnt, cur);
    fill_kernel<<<(NENT + 255) / 256, 256, 0, stream>>>(x1, x2, emb2, cur, entries);
    scatter_kernel<<<dim3(NBLK, ECH), 512, 0, stream>>>(emb1, entries, P);
    reduce_kernel<<<dim3((NBATCH * KCH + 255) / 256, ECH), 256, 0, stream>>>(P, Dm);
    termB_kernel<<<dim3(NBATCH / TI, LSEQ / 64), 320, 0, stream>>>(x2, emb2, Dm);
    fc1_kernel<<<dim3(D_MODEL / JPB, ECH), 320, 0, stream>>>(w1, Dm, Hpre);
    fc2_softmax_kernel<<<(D_MODEL + 63) / 64, 256, 0, stream>>>(Hpre, b1, w2, b2, out);
}